// Round 2
// baseline (1161.089 us; speedup 1.0000x reference)
//
#include <hip/hip_runtime.h>
#include <stdint.h>

#define N_CUST 500000
#define N_FUND 50000
#define N_EDGE 4000000
#define D_CUST 101
#define HID 64

// ---------------------------------------------------------------------------
// Kernel 1: g_f[f] = relu(x_f[f]*W_fund + b_fund) @ (W_l @ W_out)   [N_FUND,2]
// Each block recomputes A = W_l@W_out (128 entries x 64 MACs); cheap.
// ---------------------------------------------------------------------------
__global__ __launch_bounds__(256) void k_gf(
    const float* __restrict__ x_fund,   // [N_FUND]  (D_FUND == 1)
    const float* __restrict__ W_fund,   // [64]
    const float* __restrict__ b_fund,   // [64]
    const float* __restrict__ W_l,      // [64*64]
    const float* __restrict__ W_out,    // [64*2]
    float2* __restrict__ gf)            // [N_FUND]
{
    __shared__ float sA[128];   // A[h*2+j] = (W_l @ W_out)
    __shared__ float sWf[64];
    __shared__ float sBf[64];
    int t = threadIdx.x;
    if (t < 128) {
        int h = t >> 1, j = t & 1;
        float s = 0.f;
        for (int k = 0; k < 64; ++k)
            s += W_l[h * 64 + k] * W_out[k * 2 + j];
        sA[t] = s;
    } else if (t < 192) {
        sWf[t - 128] = W_fund[t - 128];
    } else {
        sBf[t - 192] = b_fund[t - 192];
    }
    __syncthreads();

    int f = blockIdx.x * 256 + t;
    if (f < N_FUND) {
        float xf = x_fund[f];
        float g0 = 0.f, g1 = 0.f;
        #pragma unroll
        for (int h = 0; h < 64; ++h) {
            float hf = fmaxf(fmaf(xf, sWf[h], sBf[h]), 0.f);
            g0 = fmaf(hf, sA[2 * h + 0], g0);
            g1 = fmaf(hf, sA[2 * h + 1], g1);
        }
        gf[f] = make_float2(g0, g1);
    }
}

// ---------------------------------------------------------------------------
// Kernel 2: edge scatter. acc[d] += gf[s]; cnt[d] += 1.
// ---------------------------------------------------------------------------
__global__ __launch_bounds__(256) void k_scatter(
    const int* __restrict__ src,
    const int* __restrict__ dst,
    const float2* __restrict__ gf,
    float* __restrict__ acc,      // [N_CUST*2]
    int* __restrict__ cnt)        // [N_CUST]
{
    int stride = gridDim.x * 256;
    for (int e = blockIdx.x * 256 + threadIdx.x; e < N_EDGE; e += stride) {
        int s = src[e];
        int d = dst[e];
        float2 g = gf[s];
        unsafeAtomicAdd(&acc[2 * d + 0], g.x);
        unsafeAtomicAdd(&acc[2 * d + 1], g.y);
        atomicAdd(&cnt[d], 1);
    }
}

// ---------------------------------------------------------------------------
// Kernel 3: fused customer pass.
// z = relu(x_c[i,:] @ W_cust + b_cust)           (101x64 MACs, W in LDS)
// out[i,:] = (acc[i]/max(cnt,1)) + z @ (W_r@W_out) + (b_l@W_out + b_out)
// ---------------------------------------------------------------------------
__global__ __launch_bounds__(256) void k_cust(
    const float* __restrict__ x_cust,   // [N_CUST*101]
    const float* __restrict__ W_cust,   // [101*64]
    const float* __restrict__ b_cust,   // [64]
    const float* __restrict__ W_r,      // [64*64]
    const float* __restrict__ W_out,    // [64*2]
    const float* __restrict__ b_l,      // [64]
    const float* __restrict__ b_out,    // [2]
    const float2* __restrict__ acc,     // [N_CUST]
    const int* __restrict__ cnt,        // [N_CUST]
    float2* __restrict__ out)           // [N_CUST]
{
    __shared__ __align__(16) float sW[D_CUST * HID];   // 25856 B, [k][h]
    __shared__ float sB[128];   // Btilde[h*2+j] = (W_r @ W_out)
    __shared__ float sbc[64];   // b_cust
    __shared__ float sc[2];     // b_l @ W_out + b_out

    int t = threadIdx.x;
    if (t < 128) {
        int h = t >> 1, j = t & 1;
        float s = 0.f;
        for (int k = 0; k < 64; ++k)
            s += W_r[h * 64 + k] * W_out[k * 2 + j];
        sB[t] = s;
    } else if (t < 192) {
        sbc[t - 128] = b_cust[t - 128];
    } else if (t < 194) {
        int j = t - 192;
        float s = b_out[j];
        for (int k = 0; k < 64; ++k)
            s += b_l[k] * W_out[k * 2 + j];
        sc[j] = s;
    }
    for (int idx = t; idx < D_CUST * HID; idx += 256)
        sW[idx] = W_cust[idx];
    __syncthreads();

    int i = blockIdx.x * 256 + t;
    if (i >= N_CUST) return;

    float a[HID];
    #pragma unroll
    for (int h = 0; h < HID; ++h) a[h] = sbc[h];

    const float* xr = x_cust + (size_t)i * D_CUST;
    float xk = xr[0];
    #pragma unroll 2
    for (int k = 0; k < D_CUST; ++k) {
        int kn = (k < D_CUST - 1) ? (k + 1) : (D_CUST - 1);
        float xn = xr[kn];                          // prefetch next
        const float4* w4 = (const float4*)(sW + k * HID);
        #pragma unroll
        for (int q = 0; q < 16; ++q) {
            float4 w = w4[q];
            a[4 * q + 0] = fmaf(xk, w.x, a[4 * q + 0]);
            a[4 * q + 1] = fmaf(xk, w.y, a[4 * q + 1]);
            a[4 * q + 2] = fmaf(xk, w.z, a[4 * q + 2]);
            a[4 * q + 3] = fmaf(xk, w.w, a[4 * q + 3]);
        }
        xk = xn;
    }

    float p0 = sc[0], p1 = sc[1];
    #pragma unroll
    for (int h = 0; h < HID; ++h) {
        float z = fmaxf(a[h], 0.f);
        p0 = fmaf(z, sB[2 * h + 0], p0);
        p1 = fmaf(z, sB[2 * h + 1], p1);
    }

    float2 s2 = acc[i];
    float cn = fmaxf((float)cnt[i], 1.0f);
    float inv = 1.0f / cn;
    out[i] = make_float2(fmaf(s2.x, inv, p0), fmaf(s2.y, inv, p1));
}

// ---------------------------------------------------------------------------
extern "C" void kernel_launch(void* const* d_in, const int* in_sizes, int n_in,
                              void* d_out, int out_size, void* d_ws, size_t ws_size,
                              hipStream_t stream) {
    const float* x_customer = (const float*)d_in[0];
    const float* x_fund     = (const float*)d_in[1];
    const int*   src_fund   = (const int*)d_in[2];
    const int*   dst_cust   = (const int*)d_in[3];
    const float* W_cust     = (const float*)d_in[4];
    const float* b_cust     = (const float*)d_in[5];
    const float* W_fund     = (const float*)d_in[6];
    const float* b_fund     = (const float*)d_in[7];
    const float* W_l        = (const float*)d_in[8];
    const float* b_l        = (const float*)d_in[9];
    const float* W_r        = (const float*)d_in[10];
    const float* W_out      = (const float*)d_in[11];
    const float* b_out      = (const float*)d_in[12];

    // workspace layout
    char* ws = (char*)d_ws;
    float2* gf  = (float2*)(ws);                 // 400,000 B
    float*  acc = (float*)(ws + 400000);         // 4,000,000 B  [N_CUST*2]
    int*    cnt = (int*)(ws + 4400000);          // 2,000,000 B
    // zero acc + cnt (contiguous 6 MB)
    hipMemsetAsync(ws + 400000, 0, 6000000, stream);

    k_gf<<<(N_FUND + 255) / 256, 256, 0, stream>>>(x_fund, W_fund, b_fund, W_l, W_out, gf);

    k_scatter<<<2048, 256, 0, stream>>>(src_fund, dst_cust, gf, acc, cnt);

    k_cust<<<(N_CUST + 255) / 256, 256, 0, stream>>>(
        x_customer, W_cust, b_cust, W_r, W_out, b_l, b_out,
        (const float2*)acc, cnt, (float2*)d_out);
}